// Round 4
// baseline (14069.502 us; speedup 1.0000x reference)
//
#include <hip/hip_runtime.h>
#include <cstdint>
#include <cstddef>

#define T_ 256
#define B_ 128
#define E_ 512
#define H_ 1024
#define BH (B_*H_)

#define AGENT __HIP_MEMORY_SCOPE_AGENT
#define RLX   __ATOMIC_RELAXED

typedef _Float16 v8h __attribute__((ext_vector_type(8)));
typedef float    v4f __attribute__((ext_vector_type(4)));

__device__ __forceinline__ float sigmoidf_(float x){ return 1.0f/(1.0f+__expf(-x)); }
__device__ __forceinline__ float tanhf_(float x){ return 1.0f - 2.0f/(__expf(2.0f*x)+1.0f); }

// 16B h-fragment read as two 8B agent-scope relaxed atomic loads: served at the
// device coherence point -> immune to stale per-XCD L2 copies, and does NOT
// require any cache invalidation (so weights stay L2-resident forever).
__device__ __forceinline__ v8h aload16(const _Float16* p) {
    const unsigned long long* q = (const unsigned long long*)p;
    unsigned long long a = __hip_atomic_load(q,     RLX, AGENT);
    unsigned long long b = __hip_atomic_load(q + 1, RLX, AGENT);
    union { unsigned long long u[2]; v8h h; } r; r.u[0] = a; r.u[1] = b; return r.h;
}

// Pack (col, col+1) half pair across adjacent lanes; even lanes publish with a
// 4B agent-scope atomic exchange (RMW executes at the coherence point ->
// device-visible once vmcnt drains, no wbL2 needed).
__device__ __forceinline__ void xchg_pair(_Float16* base, size_t off_even,
                                          _Float16 v, int lane) {
    unsigned int mine = (unsigned int)__builtin_bit_cast(unsigned short, v);
    unsigned int other = __shfl_xor(mine, 1, 64);
    if (!(lane & 1)) {
        unsigned int packed = mine | (other << 16);
        (void)__hip_atomic_exchange((unsigned int*)(base + off_even), packed, RLX, AGENT);
    }
}

// Two-level grid barrier, zero cache-maintenance. 32 leaf lines x 8 arrivals,
// 32 root pollers, 32 release lines x 7 pollers -> no line oversubscription
// (round-3 bug: 256 pollers on one line saturated the home L2 bank).
__device__ __forceinline__ void grid_barrier(unsigned int* base, int blk, unsigned int k1) {
    __syncthreads();   // drains vmcnt -> all h exchanges acked at coherence point
    if (threadIdx.x == 0) {
        const int g = blk >> 3;
        unsigned int* leaf = base + g * 32;          // 128B apart
        unsigned int* root = base + 32 * 32;
        unsigned int* rel  = base + 33 * 32 + g * 32;
        unsigned int old = __hip_atomic_fetch_add(leaf, 1u, RLX, AGENT);
        if ((old & 7u) == 7u) {                       // group finisher
            __hip_atomic_fetch_add(root, 1u, RLX, AGENT);
            while (__hip_atomic_load(root, RLX, AGENT) < 32u * k1)
                __builtin_amdgcn_s_sleep(2);
            (void)__hip_atomic_exchange(rel, k1, RLX, AGENT);
        } else {
            while (__hip_atomic_load(rel, RLX, AGENT) < k1)
                __builtin_amdgcn_s_sleep(2);
        }
    }
    __syncthreads();
}

// One K-segment: NK ksteps of K=32, chunked 8 ksteps (32 v8h in flight).
// AT: A-fragments via coherent atomic loads (h buffers); else cached (x, weights).
template<int NK, bool AT>
__device__ __forceinline__ void gemm_seg(
    v4f& aR, v4f& aZ, v4f& aN,
    const _Float16* __restrict__ A, int ap,
    const _Float16* __restrict__ Bw, int bp,
    int arow0, int bcol0, int lane)
{
    const int r = lane & 15, h4 = lane >> 4;
    const _Float16* ab = A  + (size_t)(arow0 + r) * ap + h4 * 8;
    const _Float16* bb = Bw + (size_t)(bcol0 + r) * bp + h4 * 8;
    const size_t gs = (size_t)H_ * bp;
#pragma unroll
    for (int c0 = 0; c0 < NK; c0 += 8) {
        v8h af[8], b0[8], b1[8], b2[8];
#pragma unroll
        for (int k2 = 0; k2 < 8; ++k2) {
            const int kk = (c0 + k2) * 32;
            af[k2] = AT ? aload16(ab + kk) : *(const v8h*)(ab + kk);
            b0[k2] = *(const v8h*)(bb + kk);
            b1[k2] = *(const v8h*)(bb + gs + kk);
            b2[k2] = *(const v8h*)(bb + 2 * gs + kk);
        }
#pragma unroll
        for (int k2 = 0; k2 < 8; ++k2) {
            aR = __builtin_amdgcn_mfma_f32_16x16x32_f16(af[k2], b0[k2], aR, 0,0,0);
            aZ = __builtin_amdgcn_mfma_f32_16x16x32_f16(af[k2], b1[k2], aZ, 0,0,0);
            aN = __builtin_amdgcn_mfma_f32_16x16x32_f16(af[k2], b2[k2], aN, 0,0,0);
        }
    }
}

// ---------------------------------------------------------------------------
// Persistent fused 2-layer packed-seq GRU. 256 WGs x 256 thr.
// WGs 0..127: layer0 @ t=k; 128..255: layer1 @ t=k-1. One barrier per step.
// WG tile 32 rows x 32 cols; wave (mw,cv) owns 16x16 out -> no LDS reduction.
// XCD swizzle: same-XCD WGs share 4 col-groups -> ~2.6MB weights/XCD, L2-fit.
// ---------------------------------------------------------------------------
__global__ __launch_bounds__(256, 1) void gru_persist(
    const int* __restrict__ bs, const _Float16* __restrict__ x16,
    const _Float16* __restrict__ Wi0, const _Float16* __restrict__ Wh0,
    const _Float16* __restrict__ Wi1, const _Float16* __restrict__ Wh1,
    const float* __restrict__ bias,
    float* __restrict__ h0f, float* __restrict__ h1f,
    _Float16* __restrict__ h0h, _Float16* __restrict__ h1h,
    _Float16* __restrict__ hn0,
    unsigned int* __restrict__ bar)
{
    __shared__ int bs_l[T_];
    const int blk = blockIdx.x;
    const int phase = blk >> 7, bl = blk & 127;
    const int xs = bl & 7, s = bl >> 3;
    const int rtile = (s & 3) * 32;
    const int ctile = ((s >> 2) * 8 + xs) * 32;
    const int tid = threadIdx.x, lane = tid & 63, w = tid >> 6;
    const int mw = w & 1, cv = w >> 1;          // wave's 16x16 frag in the 32x32 tile

    bs_l[tid] = bs[tid];

    const float* bb = bias + phase * 4 * H_;
    const int col = ctile + cv * 16 + (lane & 15);
    const float br_ = bb[col], bz_ = bb[H_ + col];
    const float bi_ = bb[2 * H_ + col], bh_ = bb[3 * H_ + col];
    float* hf = phase ? h1f : h0f;
    _Float16* hh = phase ? h1h : h0h;
    __syncthreads();

    for (int k = 0; k <= T_; ++k) {
        const int t = phase ? (k - 1) : k;
        const bool run = phase ? (k > 0) : (k < T_);
        if (run) {
            const int bs_t = bs_l[t];
            if (rtile < bs_t) {
                const int pr = t & 1, pw = 1 - pr;
                float hpv[4];
#pragma unroll
                for (int reg = 0; reg < 4; ++reg) {     // private fp32 master
                    const int row = rtile + mw * 16 + (lane >> 4) * 4 + reg;
                    hpv[reg] = hf[(size_t)row * H_ + col];
                }
                v4f aR{0.f,0.f,0.f,0.f}, aZ{0.f,0.f,0.f,0.f};
                v4f aNi{0.f,0.f,0.f,0.f}, aNh{0.f,0.f,0.f,0.f};
                const int ar0 = rtile + mw * 16, bc0 = ctile + cv * 16;
                if (phase == 0) {
                    gemm_seg<16,false>(aR, aZ, aNi, x16 + (size_t)t * B_ * E_, E_,
                                       Wi0, E_, ar0, bc0, lane);
                    gemm_seg<32,true >(aR, aZ, aNh, h0h + (size_t)pr * BH, H_,
                                       Wh0, H_, ar0, bc0, lane);
                } else {
                    gemm_seg<32,true >(aR, aZ, aNi, hn0 + (size_t)pr * BH, H_,
                                       Wi1, H_, ar0, bc0, lane);
                    gemm_seg<32,true >(aR, aZ, aNh, h1h + (size_t)pr * BH, H_,
                                       Wh1, H_, ar0, bc0, lane);
                }
                _Float16* hh_w = hh + (size_t)pw * BH;
                _Float16* hn0w = hn0 + (size_t)pr * BH;
#pragma unroll
                for (int reg = 0; reg < 4; ++reg) {
                    const int row = rtile + mw * 16 + (lane >> 4) * 4 + reg;
                    const size_t off  = (size_t)row * H_ + col;
                    const size_t offe = (size_t)row * H_ + (col & ~1);
                    const float hprev = hpv[reg];
                    const float rr = sigmoidf_(aR[reg] + br_);
                    const float zz = sigmoidf_(aZ[reg] + bz_);
                    const float nn = tanhf_(aNi[reg] + bi_ + rr * (aNh[reg] + bh_));
                    const float hnew = (1.0f - zz) * nn + zz * hprev;
                    const bool act = row < bs_t;
                    if (phase == 0) xchg_pair(hn0w, offe, (_Float16)hnew, lane);
                    xchg_pair(hh_w, offe, (_Float16)(act ? hnew : hprev), lane);
                    if (act) hf[off] = hnew;
                }
            }
        }
        grid_barrier(bar, blk, (unsigned)(k + 1));
    }
}

// ---------------------------------------------------------------------------
__global__ void cvt_f32_f16(const float* __restrict__ s, _Float16* __restrict__ d, int n) {
    int i = (blockIdx.x * 256 + threadIdx.x) * 8;
    if (i >= n) return;
    float4 v0 = *(const float4*)(s + i);
    float4 v1 = *(const float4*)(s + i + 4);
    v8h o = { (_Float16)v0.x, (_Float16)v0.y, (_Float16)v0.z, (_Float16)v0.w,
              (_Float16)v1.x, (_Float16)v1.y, (_Float16)v1.z, (_Float16)v1.w };
    *(v8h*)(d + i) = o;
}

__global__ void prep_bias(const float* __restrict__ bi0, const float* __restrict__ bh0,
                          const float* __restrict__ bi1, const float* __restrict__ bh1,
                          float* __restrict__ bias) {
    int tid = blockIdx.x * 256 + threadIdx.x;   // 2048 threads
    int l = tid >> 10, j = tid & 1023;
    const float* bi = l ? bi1 : bi0;
    const float* bh = l ? bh1 : bh0;
    float* o = bias + l * 4 * H_;
    o[j]          = bi[j] + bh[j];
    o[H_ + j]     = bi[H_ + j] + bh[H_ + j];
    o[2 * H_ + j] = bi[2 * H_ + j];
    o[3 * H_ + j] = bh[2 * H_ + j];
}

__global__ void gather_out(const float* __restrict__ h0f, const float* __restrict__ h1f,
                           const int* __restrict__ unsorted, float* __restrict__ out) {
    int rowid = blockIdx.x;          // 256 = L*B
    int l = rowid >> 7, b = rowid & 127;
    int src = unsorted[b];
    const float* s = (l ? h1f : h0f) + (size_t)src * H_;
    float* o = out + (size_t)rowid * H_;
    int c = threadIdx.x * 4;
    *(float4*)(o + c) = *(const float4*)(s + c);
}

// ---------------------------------------------------------------------------
extern "C" void kernel_launch(void* const* d_in, const int* in_sizes, int n_in,
                              void* d_out, int out_size, void* d_ws, size_t ws_size,
                              hipStream_t stream) {
    const float* x    = (const float*)d_in[0];
    const float* Wi0f = (const float*)d_in[1];
    const float* Wh0f = (const float*)d_in[2];
    const float* bi0  = (const float*)d_in[3];
    const float* bh0  = (const float*)d_in[4];
    const float* Wi1f = (const float*)d_in[5];
    const float* Wh1f = (const float*)d_in[6];
    const float* bi1  = (const float*)d_in[7];
    const float* bh1  = (const float*)d_in[8];
    const int*  bs       = (const int*)d_in[9];
    const int*  unsorted = (const int*)d_in[10];
    float* out = (float*)d_out;

    char* ws = (char*)d_ws;
    size_t off = 0;
    auto alloc = [&](size_t bytes) -> char* {
        char* p = ws + off;
        off += (bytes + 255) & ~(size_t)255;
        return p;
    };
    _Float16* x16 = (_Float16*)alloc((size_t)T_ * B_ * E_ * 2);
    _Float16* Wi0 = (_Float16*)alloc((size_t)3 * H_ * E_ * 2);
    _Float16* Wh0 = (_Float16*)alloc((size_t)3 * H_ * H_ * 2);
    _Float16* Wi1 = (_Float16*)alloc((size_t)3 * H_ * H_ * 2);
    _Float16* Wh1 = (_Float16*)alloc((size_t)3 * H_ * H_ * 2);
    float*    bias = (float*)alloc(2 * 4 * H_ * 4);
    char* zbase = ws + off;                       // zero-init block start
    unsigned int* bar = (unsigned int*)alloc(66 * 32 * 4);
    float*    h0f = (float*)alloc((size_t)BH * 4);
    float*    h1f = (float*)alloc((size_t)BH * 4);
    _Float16* h0h = (_Float16*)alloc((size_t)2 * BH * 2);
    _Float16* h1h = (_Float16*)alloc((size_t)2 * BH * 2);
    _Float16* hn0 = (_Float16*)alloc((size_t)2 * BH * 2);
    size_t zbytes = (size_t)((ws + off) - zbase);

    hipMemsetAsync(zbase, 0, zbytes, stream);

    cvt_f32_f16<<<(T_ * B_ * E_) / 2048, 256, 0, stream>>>(x, x16, T_ * B_ * E_);
    cvt_f32_f16<<<(3 * H_ * E_) / 2048, 256, 0, stream>>>(Wi0f, Wi0, 3 * H_ * E_);
    cvt_f32_f16<<<(3 * H_ * H_) / 2048, 256, 0, stream>>>(Wh0f, Wh0, 3 * H_ * H_);
    cvt_f32_f16<<<(3 * H_ * H_) / 2048, 256, 0, stream>>>(Wi1f, Wi1, 3 * H_ * H_);
    cvt_f32_f16<<<(3 * H_ * H_) / 2048, 256, 0, stream>>>(Wh1f, Wh1, 3 * H_ * H_);
    prep_bias<<<8, 256, 0, stream>>>(bi0, bh0, bi1, bh1, bias);

    gru_persist<<<256, 256, 0, stream>>>(bs, x16, Wi0, Wh0, Wi1, Wh1, bias,
                                         h0f, h1f, h0h, h1h, hn0, bar);

    gather_out<<<256, 256, 0, stream>>>(h0f, h1f, unsorted, out);
}

// Round 5
// 10057.838 us; speedup vs baseline: 1.3989x; 1.3989x over previous
//
#include <hip/hip_runtime.h>
#include <cstdint>
#include <cstddef>

#define T_ 256
#define B_ 128
#define E_ 512
#define H_ 1024
#define BH (B_*H_)

#define AGENT __HIP_MEMORY_SCOPE_AGENT
#define RLX   __ATOMIC_RELAXED

typedef _Float16 v8h __attribute__((ext_vector_type(8)));
typedef float    v4f __attribute__((ext_vector_type(4)));
typedef unsigned long long u64;

__device__ __forceinline__ float sigmoidf_(float x){ return 1.0f/(1.0f+__expf(-x)); }
__device__ __forceinline__ float tanhf_(float x){ return 1.0f - 2.0f/(__expf(2.0f*x)+1.0f); }

// Two-level grid barrier, zero cache maintenance (validated round 4).
// 32 leaf lines x 8 arrivals, 32 root pollers, per-group release lines.
__device__ __forceinline__ void grid_barrier(unsigned int* base, int blk, unsigned int k1) {
    __syncthreads();   // drains vmcnt: all device-scope stores acked at L3 first
    if (threadIdx.x == 0) {
        const int g = blk >> 3;
        unsigned int* leaf = base + g * 32;
        unsigned int* root = base + 32 * 32;
        unsigned int* rel  = base + 33 * 32 + g * 32;
        unsigned int old = __hip_atomic_fetch_add(leaf, 1u, RLX, AGENT);
        if ((old & 7u) == 7u) {
            __hip_atomic_fetch_add(root, 1u, RLX, AGENT);
            while (__hip_atomic_load(root, RLX, AGENT) < 32u * k1)
                __builtin_amdgcn_s_sleep(2);
            (void)__hip_atomic_exchange(rel, k1, RLX, AGENT);
        } else {
            while (__hip_atomic_load(rel, RLX, AGENT) < k1)
                __builtin_amdgcn_s_sleep(2);
        }
    }
    __syncthreads();
}

#define APITCH 520   // halves; 1040B rows -> ds_read_b128 is 2-way (free)
#define OPITCH 72

// Stage one 16-row x 512-half A chunk into registers (64B/thread as 8x8B).
// Thread t: row = t>>4, piece i at halves (t&15)*4 + i*64 -> threads 0..15
// cover 128B contiguous per piece (coalesced); AT: device-scope (h buffers).
template<bool AT>
__device__ __forceinline__ void stage_load(u64 (&regs)[8],
    const _Float16* __restrict__ src, int ap, int row0, int kbase, int tid) {
    const int r = tid >> 4, b = tid & 15;
    const _Float16* p = src + (size_t)(row0 + r) * ap + kbase + b * 4;
#pragma unroll
    for (int i = 0; i < 8; ++i) {
        const u64* q = (const u64*)(p + i * 64);
        regs[i] = AT ? __hip_atomic_load(q, RLX, AGENT) : *q;
    }
}
// LDS banks for piece i: word (260r + 2b + 32i) % 32 = (4r + 2b) % 32 ->
// 64 lanes cover all 32 banks once per piece: conflict-free.
__device__ __forceinline__ void stage_write(const u64 (&regs)[8],
    _Float16 (&buf)[16][APITCH], int tid) {
    const int r = tid >> 4, b = tid & 15;
#pragma unroll
    for (int i = 0; i < 8; ++i)
        *(u64*)&buf[r][b * 4 + i * 64] = regs[i];
}

// 16 ksteps (512 halves) of 16x16x32 f16 MFMA over a staged A chunk.
// B direct from L2 (cached, XCD-resident slice). 3 gates.
__device__ __forceinline__ void mfma_chunk(v4f& aR, v4f& aZ, v4f& aN,
    const _Float16 (&buf)[16][APITCH],
    const _Float16* __restrict__ Bw, int bp, int bcol, int kbase, int lane) {
    const int r = lane & 15, hi = lane >> 4;
    const _Float16* bb = Bw + (size_t)(bcol + r) * bp + kbase + hi * 8;
    const size_t gs = (size_t)H_ * bp;
#pragma unroll
    for (int sub = 0; sub < 2; ++sub) {
        v8h B0[8], B1[8], B2[8], Av[8];
#pragma unroll
        for (int j = 0; j < 8; ++j) {
            const int kk = (sub * 8 + j) * 32;
            B0[j] = *(const v8h*)(bb + kk);
            B1[j] = *(const v8h*)(bb + gs + kk);
            B2[j] = *(const v8h*)(bb + 2 * gs + kk);
            Av[j] = *(const v8h*)&buf[r][sub * 256 + j * 32 + hi * 8];
        }
#pragma unroll
        for (int j = 0; j < 8; ++j) {
            aR = __builtin_amdgcn_mfma_f32_16x16x32_f16(Av[j], B0[j], aR, 0,0,0);
            aZ = __builtin_amdgcn_mfma_f32_16x16x32_f16(Av[j], B1[j], aZ, 0,0,0);
            aN = __builtin_amdgcn_mfma_f32_16x16x32_f16(Av[j], B2[j], aN, 0,0,0);
        }
    }
}

// ---------------------------------------------------------------------------
// Persistent fused 2-layer packed-seq GRU. 256 WGs x 256 thr, 1 WG/CU.
// WGs 0..127: layer0 @ t=k; 128..255: layer1 @ t=k-1. One barrier per step.
// WG tile 16 rows x 64 cols; wave w owns cols [w*16,+16) -> no K-split reduce.
// h exchange: 8B relaxed agent atomics (plain ld/st, no RMW) -> L3-coherent,
// no cache-wide maintenance -> weights stay L2-resident (per-XCD ~2.7MB).
// ---------------------------------------------------------------------------
__global__ __launch_bounds__(256, 1) void gru_persist(
    const int* __restrict__ bs, const _Float16* __restrict__ x16,
    const _Float16* __restrict__ Wi0, const _Float16* __restrict__ Wh0,
    const _Float16* __restrict__ Wi1, const _Float16* __restrict__ Wh1,
    const float* __restrict__ bias,
    float* __restrict__ h0f, float* __restrict__ h1f,
    _Float16* __restrict__ h0h, _Float16* __restrict__ h1h,
    _Float16* __restrict__ hn0,
    unsigned int* __restrict__ bar)
{
    __shared__ _Float16 Abuf[2][16][APITCH];
    __shared__ _Float16 Otile[2][16][OPITCH];   // [0]=h-shadow, [1]=hn0
    __shared__ int bs_l[T_];

    const int blk = blockIdx.x;
    const int phase = blk >> 7, bl = blk & 127;
    const int xcd = bl & 7, idx = bl >> 3;      // idx in [0,16)
    const int rtile = (idx & 7) * 16;
    const int ctile = (xcd * 2 + (idx >> 3)) * 64;
    const int tid = threadIdx.x, lane = tid & 63, w = tid >> 6;

    bs_l[tid] = bs[tid];

    const float* bb = bias + phase * 4 * H_;
    const int colw = w * 16 + (lane & 15);      // [0,64) within tile
    const int col = ctile + colw;
    const float br_ = bb[col], bz_ = bb[H_ + col];
    const float bi_ = bb[2 * H_ + col], bh_ = bb[3 * H_ + col];
    float* hf = phase ? h1f : h0f;
    _Float16* hh = phase ? h1h : h0h;
    const int bcol = ctile + w * 16;
    __syncthreads();

    for (int k = 0; k <= T_; ++k) {
        const int t = phase ? (k - 1) : k;
        const bool run = phase ? (k > 0) : (k < T_);
        if (run) {
            const int bs_t = bs_l[t];
            if (rtile < bs_t) {
                const int pr = t & 1, pw = 1 - pr;
                v4f aR{0.f,0.f,0.f,0.f}, aZ{0.f,0.f,0.f,0.f};
                v4f aNi{0.f,0.f,0.f,0.f}, aNh{0.f,0.f,0.f,0.f};
                u64 regs[8];
                // Chained chunk pipeline: stage-load of chunk c+1 issues
                // before MFMAs of chunk c -> only chunk0 latency exposed.
                if (phase == 0) {
                    const _Float16* xr = x16 + (size_t)t * B_ * E_;
                    const _Float16* hr = h0h + (size_t)pr * BH;
                    stage_load<false>(regs, xr, E_, rtile, 0, tid);
                    __syncthreads(); stage_write(regs, Abuf[0], tid); __syncthreads();
                    stage_load<true>(regs, hr, H_, rtile, 0, tid);
                    mfma_chunk(aR, aZ, aNi, Abuf[0], Wi0, E_, bcol, 0, lane);
                    __syncthreads(); stage_write(regs, Abuf[1], tid); __syncthreads();
                    stage_load<true>(regs, hr, H_, rtile, 512, tid);
                    mfma_chunk(aR, aZ, aNh, Abuf[1], Wh0, H_, bcol, 0, lane);
                    __syncthreads(); stage_write(regs, Abuf[0], tid); __syncthreads();
                    mfma_chunk(aR, aZ, aNh, Abuf[0], Wh0, H_, bcol, 512, lane);
                } else {
                    const _Float16* nr = hn0 + (size_t)pr * BH;
                    const _Float16* hr = h1h + (size_t)pr * BH;
                    stage_load<true>(regs, nr, H_, rtile, 0, tid);
                    __syncthreads(); stage_write(regs, Abuf[0], tid); __syncthreads();
                    stage_load<true>(regs, nr, H_, rtile, 512, tid);
                    mfma_chunk(aR, aZ, aNi, Abuf[0], Wi1, H_, bcol, 0, lane);
                    __syncthreads(); stage_write(regs, Abuf[1], tid); __syncthreads();
                    stage_load<true>(regs, hr, H_, rtile, 0, tid);
                    mfma_chunk(aR, aZ, aNi, Abuf[1], Wi1, H_, bcol, 512, lane);
                    __syncthreads(); stage_write(regs, Abuf[0], tid); __syncthreads();
                    stage_load<true>(regs, hr, H_, rtile, 512, tid);
                    mfma_chunk(aR, aZ, aNh, Abuf[0], Wh1, H_, bcol, 0, lane);
                    __syncthreads(); stage_write(regs, Abuf[1], tid); __syncthreads();
                    mfma_chunk(aR, aZ, aNh, Abuf[1], Wh1, H_, bcol, 512, lane);
                }
                // epilogue: C layout col=lane&15, row=(lane>>4)*4+reg
                const int q = lane >> 4;
#pragma unroll
                for (int reg = 0; reg < 4; ++reg) {
                    const int rowt = q * 4 + reg;           // [0,16)
                    const int row = rtile + rowt;
                    const size_t off = (size_t)row * H_ + col;
                    const float hprev = hf[off];
                    const float rr = sigmoidf_(aR[reg] + br_);
                    const float zz = sigmoidf_(aZ[reg] + bz_);
                    const float nn = tanhf_(aNi[reg] + bi_ + rr * (aNh[reg] + bh_));
                    const float hnew = (1.0f - zz) * nn + zz * hprev;
                    const bool act = row < bs_t;
                    Otile[0][rowt][colw] = (_Float16)(act ? hnew : hprev);
                    if (phase == 0) Otile[1][rowt][colw] = (_Float16)hnew;
                    if (act) hf[off] = hnew;
                }
                __syncthreads();
                // publish tiles: coalesced 8B device-scope plain-atomic stores
                {
                    const int r = tid >> 4, c4 = (tid & 15) * 4;
                    const size_t goff = (size_t)(rtile + r) * H_ + ctile + c4;
                    _Float16* hh_w = hh + (size_t)pw * BH;
                    u64 v0 = *(const u64*)&Otile[0][r][c4];
                    __hip_atomic_store((u64*)(hh_w + goff), v0, RLX, AGENT);
                    if (phase == 0) {
                        _Float16* hn0w = hn0 + (size_t)pr * BH;
                        u64 v1 = *(const u64*)&Otile[1][r][c4];
                        __hip_atomic_store((u64*)(hn0w + goff), v1, RLX, AGENT);
                    }
                }
            }
        }
        grid_barrier(bar, blk, (unsigned)(k + 1));
    }
}

// ---------------------------------------------------------------------------
__global__ void cvt_f32_f16(const float* __restrict__ s, _Float16* __restrict__ d, int n) {
    int i = (blockIdx.x * 256 + threadIdx.x) * 8;
    if (i >= n) return;
    float4 v0 = *(const float4*)(s + i);
    float4 v1 = *(const float4*)(s + i + 4);
    v8h o = { (_Float16)v0.x, (_Float16)v0.y, (_Float16)v0.z, (_Float16)v0.w,
              (_Float16)v1.x, (_Float16)v1.y, (_Float16)v1.z, (_Float16)v1.w };
    *(v8h*)(d + i) = o;
}

__global__ void prep_bias(const float* __restrict__ bi0, const float* __restrict__ bh0,
                          const float* __restrict__ bi1, const float* __restrict__ bh1,
                          float* __restrict__ bias) {
    int tid = blockIdx.x * 256 + threadIdx.x;   // 2048 threads
    int l = tid >> 10, j = tid & 1023;
    const float* bi = l ? bi1 : bi0;
    const float* bh = l ? bh1 : bh0;
    float* o = bias + l * 4 * H_;
    o[j]          = bi[j] + bh[j];
    o[H_ + j]     = bi[H_ + j] + bh[H_ + j];
    o[2 * H_ + j] = bi[2 * H_ + j];
    o[3 * H_ + j] = bh[2 * H_ + j];
}

__global__ void gather_out(const float* __restrict__ h0f, const float* __restrict__ h1f,
                           const int* __restrict__ unsorted, float* __restrict__ out) {
    int rowid = blockIdx.x;          // 256 = L*B
    int l = rowid >> 7, b = rowid & 127;
    int src = unsorted[b];
    const float* s = (l ? h1f : h0f) + (size_t)src * H_;
    float* o = out + (size_t)rowid * H_;
    int c = threadIdx.x * 4;
    *(float4*)(o + c) = *(const float4*)(s + c);
}

// ---------------------------------------------------------------------------
extern "C" void kernel_launch(void* const* d_in, const int* in_sizes, int n_in,
                              void* d_out, int out_size, void* d_ws, size_t ws_size,
                              hipStream_t stream) {
    const float* x    = (const float*)d_in[0];
    const float* Wi0f = (const float*)d_in[1];
    const float* Wh0f = (const float*)d_in[2];
    const float* bi0  = (const float*)d_in[3];
    const float* bh0  = (const float*)d_in[4];
    const float* Wi1f = (const float*)d_in[5];
    const float* Wh1f = (const float*)d_in[6];
    const float* bi1  = (const float*)d_in[7];
    const float* bh1  = (const float*)d_in[8];
    const int*  bs       = (const int*)d_in[9];
    const int*  unsorted = (const int*)d_in[10];
    float* out = (float*)d_out;

    char* ws = (char*)d_ws;
    size_t off = 0;
    auto alloc = [&](size_t bytes) -> char* {
        char* p = ws + off;
        off += (bytes + 255) & ~(size_t)255;
        return p;
    };
    _Float16* x16 = (_Float16*)alloc((size_t)T_ * B_ * E_ * 2);
    _Float16* Wi0 = (_Float16*)alloc((size_t)3 * H_ * E_ * 2);
    _Float16* Wh0 = (_Float16*)alloc((size_t)3 * H_ * H_ * 2);
    _Float16* Wi1 = (_Float16*)alloc((size_t)3 * H_ * H_ * 2);
    _Float16* Wh1 = (_Float16*)alloc((size_t)3 * H_ * H_ * 2);
    float*    bias = (float*)alloc(2 * 4 * H_ * 4);
    char* zbase = ws + off;                       // zero-init block start
    unsigned int* bar = (unsigned int*)alloc(66 * 32 * 4);
    float*    h0f = (float*)alloc((size_t)BH * 4);
    float*    h1f = (float*)alloc((size_t)BH * 4);
    _Float16* h0h = (_Float16*)alloc((size_t)2 * BH * 2);
    _Float16* h1h = (_Float16*)alloc((size_t)2 * BH * 2);
    _Float16* hn0 = (_Float16*)alloc((size_t)2 * BH * 2);
    size_t zbytes = (size_t)((ws + off) - zbase);

    hipMemsetAsync(zbase, 0, zbytes, stream);

    cvt_f32_f16<<<(T_ * B_ * E_) / 2048, 256, 0, stream>>>(x, x16, T_ * B_ * E_);
    cvt_f32_f16<<<(3 * H_ * E_) / 2048, 256, 0, stream>>>(Wi0f, Wi0, 3 * H_ * E_);
    cvt_f32_f16<<<(3 * H_ * H_) / 2048, 256, 0, stream>>>(Wh0f, Wh0, 3 * H_ * H_);
    cvt_f32_f16<<<(3 * H_ * H_) / 2048, 256, 0, stream>>>(Wi1f, Wi1, 3 * H_ * H_);
    cvt_f32_f16<<<(3 * H_ * H_) / 2048, 256, 0, stream>>>(Wh1f, Wh1, 3 * H_ * H_);
    prep_bias<<<8, 256, 0, stream>>>(bi0, bh0, bi1, bh1, bias);

    gru_persist<<<256, 256, 0, stream>>>(bs, x16, Wi0, Wh0, Wi1, Wh1, bias,
                                         h0f, h1f, h0h, h1h, hn0, bar);

    gather_out<<<256, 256, 0, stream>>>(h0f, h1f, unsorted, out);
}